// Round 1
// baseline (292.840 us; speedup 1.0000x reference)
//
#include <hip/hip_runtime.h>

// S4 recurrence -> causal convolution.
//   y[b,t] = d*u0[b,t] + sum_{s<=t} k[t-s]*u0[b,s],  k[j] = c^T Abar^j bbar
//   Abar = expm(dt*A) (scaling+squaring, deg-15 Taylor, Paterson-Stockmeyer)
//   bbar = dt*phi1(dt*A)*B via phi1 vector doubling (no solve needed)
//   k[64q+r] = (c^T P64^q) . (Abar^r bbar)   (bilinear 64x64 split)
// ws layout (floats): [0,4096) k | [4096,20480) u0 | 20480 gX | 24576 gX2
//                     | 28672 gX3 | 32768 gXT | 36864 gAbarT   (=160 KiB)

__device__ __forceinline__ void mm64(const float* Ma, const float* Mb, float* Mc) {
  // Mc = Ma*Mb, 64x64 row-major, 256 threads. Mc must not alias Ma/Mb.
  __syncthreads();
  const int lane = threadIdx.x & 63;
  const int wv = threadIdx.x >> 6;
  float acc[16];
#pragma unroll
  for (int i = 0; i < 16; ++i) acc[i] = 0.f;
  for (int k4 = 0; k4 < 64; k4 += 4) {
    const float b0 = Mb[(k4 + 0) * 64 + lane];
    const float b1 = Mb[(k4 + 1) * 64 + lane];
    const float b2 = Mb[(k4 + 2) * 64 + lane];
    const float b3 = Mb[(k4 + 3) * 64 + lane];
#pragma unroll
    for (int i = 0; i < 16; ++i) {
      const float4 a = *(const float4*)(Ma + (wv * 16 + i) * 64 + k4);
      acc[i] = fmaf(a.x, b0, acc[i]);
      acc[i] = fmaf(a.y, b1, acc[i]);
      acc[i] = fmaf(a.z, b2, acc[i]);
      acc[i] = fmaf(a.w, b3, acc[i]);
    }
  }
  __syncthreads();
#pragma unroll
  for (int i = 0; i < 16; ++i) Mc[(wv * 16 + i) * 64 + lane] = acc[i];
  __syncthreads();
}

__device__ __forceinline__ void mv64_T(const float* MT, const float* vin,
                                       float* vout, float* vscr) {
  // vout_i = sum_k MT[k*64+i]*vin[k]  (i.e. M*v given M^T, or M^T*v given M)
  const int lane = threadIdx.x & 63;
  const int wv = threadIdx.x >> 6;
  const int k0 = wv * 16;
  float p = 0.f;
#pragma unroll
  for (int kk = 0; kk < 16; ++kk)
    p = fmaf(MT[(k0 + kk) * 64 + lane], vin[k0 + kk], p);
  vscr[wv * 64 + lane] = p;
  __syncthreads();
  if (threadIdx.x < 64)
    vout[lane] = vscr[lane] + vscr[64 + lane] + vscr[128 + lane] + vscr[192 + lane];
  __syncthreads();
}

__device__ __forceinline__ void transpose64(float* dst, const float* src) {
  __syncthreads();
#pragma unroll
  for (int i = 0; i < 16; ++i) {
    const int e = threadIdx.x + 256 * i;
    dst[e] = src[((e & 63) << 6) | (e >> 6)];
  }
  __syncthreads();
}

__device__ __forceinline__ void buildG(float* dst, const float* X, const float* X2,
                                       const float* X3, float c0, float c1, float c2,
                                       float c3, bool add) {
  __syncthreads();
#pragma unroll
  for (int i = 0; i < 16; ++i) {
    const int e = threadIdx.x + 256 * i;
    float v = c1 * X[e] + c2 * X2[e] + c3 * X3[e];
    if ((e >> 6) == (e & 63)) v += c0;
    dst[e] = add ? dst[e] + v : v;
  }
  __syncthreads();
}

__global__ __launch_bounds__(256) void s4_setup(const float* __restrict__ A,
                                                const float* __restrict__ Bv,
                                                const float* __restrict__ Cv,
                                                const float* __restrict__ logdt,
                                                float* __restrict__ ws) {
  __shared__ __align__(16) float L0[4096];
  __shared__ __align__(16) float L1b[4096];
  __shared__ __align__(16) float L2b[4096];
  __shared__ float va0[64], vb0[64], vg[64], vscr[256];
  __shared__ int s_s;

  float* kout = ws;
  float* gX  = ws + 20480;
  float* gX2 = ws + 24576;
  float* gX3 = ws + 28672;
  float* gXT = ws + 32768;
  float* gAT = ws + 36864;

  const int tid = threadIdx.x, lane = tid & 63, wv = tid >> 6;
  const float dt = expf(logdt[0]);

  const float invf[17] = {1.f, 1.f, 1.f / 2.f, 1.f / 6.f, 1.f / 24.f, 1.f / 120.f,
                          1.f / 720.f, 1.f / 5040.f, 1.f / 40320.f, 1.f / 362880.f,
                          1.f / 3628800.f, 1.f / 39916800.f, 1.f / 479001600.f,
                          1.f / 6.2270208e9f, 1.f / 8.71782912e10f,
                          1.f / 1.307674368e12f, 1.f / 2.0922789888e13f};

  // ---- 1-norm of M = dt*A -> scaling exponent s ----
  {
    float p = 0.f;
#pragma unroll
    for (int r = 0; r < 16; ++r) p += fabsf(A[(wv * 16 + r) * 64 + lane]);
    vscr[wv * 64 + lane] = p;
    __syncthreads();
    if (tid == 0) {
      float mx = 0.f;
      for (int j = 0; j < 64; ++j) {
        float cs = vscr[j] + vscr[64 + j] + vscr[128 + j] + vscr[192 + j];
        mx = fmaxf(mx, cs);
      }
      mx *= dt;
      int s = 0;
      while (mx > 1.0f && s < 24) { mx *= 0.5f; ++s; }
      s_s = s;
    }
    __syncthreads();
  }
  const int sq = s_s;
  const float scl = ldexpf(dt, -sq);

  // ---- X = M/2^s : LDS copy (L0), global copy (gX), global transpose (gXT) ----
#pragma unroll
  for (int i = 0; i < 16; ++i) {
    const int e = tid + 256 * i;
    const float x = A[e] * scl;
    L0[e] = x;
    gX[e] = x;
    gXT[((e & 63) << 6) | (e >> 6)] = x;
  }
  __syncthreads();

  // ---- g = phi1(X)*B via Taylor (uses gXT) ----
  if (tid < 64) { va0[lane] = Bv[lane]; vg[lane] = Bv[lane]; }
  __syncthreads();
  {
    float* vin = va0;
    float* vout = vb0;
#pragma unroll
    for (int k = 1; k <= 15; ++k) {
      mv64_T(gXT, vin, vout, vscr);
      if (tid < 64) vg[lane] = fmaf(vout[lane], invf[k + 1], vg[lane]);
      float* t = vin; vin = vout; vout = t;
    }
  }

  // ---- Taylor-15 e^X via Paterson-Stockmeyer ----
  mm64(L0, L0, L1b);                       // X2
#pragma unroll
  for (int i = 0; i < 16; ++i) { const int e = tid + 256 * i; gX2[e] = L1b[e]; }
  mm64(L1b, L0, L2b);                      // X3
#pragma unroll
  for (int i = 0; i < 16; ++i) { const int e = tid + 256 * i; gX3[e] = L2b[e]; }
  mm64(L1b, L1b, L0);                      // X4 -> L0
  buildG(L2b, gX, gX2, gX3, invf[12], invf[13], invf[14], invf[15], false);
  mm64(L2b, L0, L1b);
  buildG(L1b, gX, gX2, gX3, invf[8], invf[9], invf[10], invf[11], true);
  mm64(L1b, L0, L2b);
  buildG(L2b, gX, gX2, gX3, invf[4], invf[5], invf[6], invf[7], true);
  mm64(L2b, L0, L1b);
  buildG(L1b, gX, gX2, gX3, invf[0], invf[1], invf[2], invf[3], true);

  float* F = L1b;    // e^X
  float* Falt = L2b;
  float* S = L0;     // scratch (X4 dead)

  // ---- s squarings, with phi1-vector doubling: g <- (F+I)g/2 ----
  for (int it = 0; it < sq; ++it) {
    transpose64(S, F);
    mv64_T(S, vg, va0, vscr);
    if (tid < 64) vg[lane] = 0.5f * (va0[lane] + vg[lane]);
    mm64(F, F, Falt);
    float* t = F; F = Falt; Falt = t;
  }

  // ---- bvec = dt*g ; Abar^T -> global ----
  if (tid < 64) va0[lane] = dt * vg[lane];
#pragma unroll
  for (int i = 0; i < 16; ++i) {
    const int e = tid + 256 * i;
    gAT[e] = F[((e & 63) << 6) | (e >> 6)];
  }
  __syncthreads();

  // ---- P64 = Abar^64 ----
  mm64(F, F, S);        // P2
  mm64(S, S, Falt);     // P4
  mm64(Falt, Falt, S);  // P8
  mm64(S, S, Falt);     // P16
  mm64(Falt, Falt, S);  // P32
  mm64(S, S, Falt);     // P64 -> Falt
  float* P64 = Falt;
  float* brT = S;       // brT[i*64+r] = (Abar^r bvec)_i
  float* cqT = F;       // cqT[i*64+q] = ((P64^T)^q c)_i   (Abar in LDS no longer needed)

  // ---- br chain ----
  if (tid < 64) brT[lane * 64 + 0] = va0[lane];
  __syncthreads();
  {
    float* vin = va0;
    float* vout = vb0;
    for (int r = 1; r < 64; ++r) {
      mv64_T(gAT, vin, vout, vscr);
      if (tid < 64) brT[lane * 64 + r] = vout[lane];
      float* t = vin; vin = vout; vout = t;
    }
  }
  __syncthreads();

  // ---- cq chain ----
  if (tid < 64) { va0[lane] = Cv[lane]; cqT[lane * 64 + 0] = Cv[lane]; }
  __syncthreads();
  {
    float* vin = va0;
    float* vout = vb0;
    for (int q = 1; q < 64; ++q) {
      mv64_T(P64, vin, vout, vscr);  // = P64^T * vin
      if (tid < 64) cqT[lane * 64 + q] = vout[lane];
      float* t = vin; vin = vout; vout = t;
    }
  }
  __syncthreads();

  // ---- k[64q+r] = sum_i cqT[i][q]*brT[i][r] ----
  {
    float acck[16];
#pragma unroll
    for (int j = 0; j < 16; ++j) acck[j] = 0.f;
    for (int i = 0; i < 64; ++i) {
      const float bv = brT[i * 64 + lane];
#pragma unroll
      for (int j = 0; j < 16; ++j)
        acck[j] = fmaf(cqT[i * 64 + wv * 16 + j], bv, acck[j]);
    }
#pragma unroll
    for (int j = 0; j < 16; ++j) kout[(wv * 16 + j) * 64 + lane] = acck[j];
  }
}

__global__ __launch_bounds__(256) void s4_extract(const float* __restrict__ u,
                                                  float* __restrict__ u0) {
  const int i = blockIdx.x * 256 + threadIdx.x;  // 0..16383
  u0[i] = u[(size_t)i * 1024];
}

__global__ __launch_bounds__(256) void s4_conv(const float* __restrict__ u0,
                                               const float* __restrict__ kv,
                                               const float* __restrict__ Dp,
                                               float4* __restrict__ out) {
  const int bid = blockIdx.x;
  const int t = bid & 4095;
  const int b = bid >> 12;
  const float* ub = u0 + (b << 12);
  float acc = 0.f;
  for (int s = threadIdx.x; s <= t; s += 256) acc += kv[t - s] * ub[s];
#pragma unroll
  for (int off = 32; off > 0; off >>= 1) acc += __shfl_down(acc, off);
  __shared__ float red[4];
  const int wv = threadIdx.x >> 6;
  if ((threadIdx.x & 63) == 0) red[wv] = acc;
  __syncthreads();
  const float y = red[0] + red[1] + red[2] + red[3] + Dp[0] * ub[t];
  out[(size_t)bid * 256 + threadIdx.x] = make_float4(y, y, y, y);
}

extern "C" void kernel_launch(void* const* d_in, const int* in_sizes, int n_in,
                              void* d_out, int out_size, void* d_ws, size_t ws_size,
                              hipStream_t stream) {
  const float* u  = (const float*)d_in[0];
  const float* A  = (const float*)d_in[1];
  const float* B  = (const float*)d_in[2];
  const float* C  = (const float*)d_in[3];
  const float* D  = (const float*)d_in[4];
  const float* ld = (const float*)d_in[5];
  float* ws = (float*)d_ws;       // needs >= 163840 bytes
  float* kbuf = ws;
  float* u0 = ws + 4096;

  s4_extract<<<64, 256, 0, stream>>>(u, u0);
  s4_setup<<<1, 256, 0, stream>>>(A, B, C, ld, ws);
  s4_conv<<<16384, 256, 0, stream>>>(u0, kbuf, D, (float4*)d_out);
}

// Round 2
// 239.769 us; speedup vs baseline: 1.2213x; 1.2213x over previous
//
#include <hip/hip_runtime.h>

// S4 recurrence -> causal convolution y[b,t] = d*u0[b,t] + sum_{j<=t} k[j]*u0[b,t-j],
// k[j] = c^T Abar^j bbar.  Abar = expm(dt*A) (scale+square, Taylor-15 PS);
// bbar = dt*phi1(dt*A)*B via phi1 doubling; k via 64x64 bilinear split with
// SUBSPACE DOUBLING (6 matmul-steps per chain instead of 63 matvecs).
// ws floats: [0,4096) k | [4096,20480) u0 | 20480 gX | 24576 gX2 | 28672 gX3
//            | 32768 gBR   (147456 B total)

#define NT 1024

__device__ __forceinline__ void mm64(const float* Ma, const float* Mb, float* Mc) {
  // Mc = Ma*Mb, 64x64 row-major, 1024 threads. Mc must not alias Ma/Mb.
  __syncthreads();
  const int lane = threadIdx.x & 63;
  const int g = threadIdx.x >> 6;  // 0..15, 4 rows each
  float acc0 = 0.f, acc1 = 0.f, acc2 = 0.f, acc3 = 0.f;
  for (int k4 = 0; k4 < 64; k4 += 4) {
    const float b0 = Mb[(k4 + 0) * 64 + lane];
    const float b1 = Mb[(k4 + 1) * 64 + lane];
    const float b2 = Mb[(k4 + 2) * 64 + lane];
    const float b3 = Mb[(k4 + 3) * 64 + lane];
    const float4 a0 = *(const float4*)(Ma + (g * 4 + 0) * 64 + k4);
    const float4 a1 = *(const float4*)(Ma + (g * 4 + 1) * 64 + k4);
    const float4 a2 = *(const float4*)(Ma + (g * 4 + 2) * 64 + k4);
    const float4 a3 = *(const float4*)(Ma + (g * 4 + 3) * 64 + k4);
    acc0 = fmaf(a0.x, b0, fmaf(a0.y, b1, fmaf(a0.z, b2, fmaf(a0.w, b3, acc0))));
    acc1 = fmaf(a1.x, b0, fmaf(a1.y, b1, fmaf(a1.z, b2, fmaf(a1.w, b3, acc1))));
    acc2 = fmaf(a2.x, b0, fmaf(a2.y, b1, fmaf(a2.z, b2, fmaf(a2.w, b3, acc2))));
    acc3 = fmaf(a3.x, b0, fmaf(a3.y, b1, fmaf(a3.z, b2, fmaf(a3.w, b3, acc3))));
  }
  __syncthreads();
  Mc[(g * 4 + 0) * 64 + lane] = acc0;
  Mc[(g * 4 + 1) * 64 + lane] = acc1;
  Mc[(g * 4 + 2) * 64 + lane] = acc2;
  Mc[(g * 4 + 3) * 64 + lane] = acc3;
  __syncthreads();
}

__device__ __forceinline__ void mv64row(const float* M, const float* vin,
                                        float* vout, float* vscr) {
  // vout = M * vin (row dot), M 64x64 row-major in LDS, 1024 threads.
  const int r = threadIdx.x & 63;
  const int c16 = threadIdx.x >> 6;
  const float4 m = *(const float4*)(M + r * 64 + c16 * 4);
  const float p = fmaf(m.x, vin[c16 * 4 + 0],
                  fmaf(m.y, vin[c16 * 4 + 1],
                  fmaf(m.z, vin[c16 * 4 + 2], m.w * vin[c16 * 4 + 3])));
  vscr[c16 * 64 + r] = p;
  __syncthreads();
  if (threadIdx.x < 64) {
    float s = 0.f;
#pragma unroll
    for (int c = 0; c < 16; ++c) s += vscr[c * 64 + threadIdx.x];
    vout[threadIdx.x] = s;
  }
  __syncthreads();
}

__device__ __forceinline__ void wmul(const float* P, float* V, int wlog) {
  // V[:, w..2w) = P * V[:, 0..w),  w = 1<<wlog.  In-place safe (disjoint cols).
  const int w = 1 << wlog;
  const int nout = 64 << wlog;
  __syncthreads();
  for (int o = threadIdx.x; o < nout; o += NT) {
    const int c = o & (w - 1);
    const int i = o >> wlog;
    float acc = 0.f;
    for (int k4 = 0; k4 < 64; k4 += 4) {
      const float4 p = *(const float4*)(P + i * 64 + k4);
      acc = fmaf(p.x, V[(k4 + 0) * 64 + c],
            fmaf(p.y, V[(k4 + 1) * 64 + c],
            fmaf(p.z, V[(k4 + 2) * 64 + c],
            fmaf(p.w, V[(k4 + 3) * 64 + c], acc))));
    }
    V[i * 64 + w + c] = acc;
  }
  __syncthreads();
}

__device__ __forceinline__ void buildG(float* dst, const float* gX, const float* gX2,
                                       const float* gX3, float c0, float c1, float c2,
                                       float c3, bool add) {
  __syncthreads();
#pragma unroll
  for (int ii = 0; ii < 4; ++ii) {
    const int e = threadIdx.x + NT * ii;
    float v = c1 * gX[e] + c2 * gX2[e] + c3 * gX3[e];
    if ((e >> 6) == (e & 63)) v += c0;
    dst[e] = add ? dst[e] + v : v;
  }
  __syncthreads();
}

__global__ __launch_bounds__(NT) void s4_setup_ext(const float* __restrict__ u,
                                                   const float* __restrict__ A,
                                                   const float* __restrict__ Bv,
                                                   const float* __restrict__ Cv,
                                                   const float* __restrict__ logdt,
                                                   float* __restrict__ ws) {
  if (blockIdx.x > 0) {
    // extract u0: blocks 1..16, one element per thread
    const int idx = (blockIdx.x - 1) * NT + threadIdx.x;  // 0..16383
    ws[4096 + idx] = u[(size_t)idx * 1024];
    return;
  }

  __shared__ __align__(16) float M0[4096];
  __shared__ __align__(16) float M1[4096];
  __shared__ __align__(16) float M2[4096];
  __shared__ float va0[64], vb0[64], vg[64], vscr[NT];
  __shared__ int s_s;

  float* kout = ws;
  float* gX  = ws + 20480;
  float* gX2 = ws + 24576;
  float* gX3 = ws + 28672;
  float* gBR = ws + 32768;

  const int tid = threadIdx.x;
  const float dt = expf(logdt[0]);

  const float invf[17] = {1.f, 1.f, 1.f / 2.f, 1.f / 6.f, 1.f / 24.f, 1.f / 120.f,
                          1.f / 720.f, 1.f / 5040.f, 1.f / 40320.f, 1.f / 362880.f,
                          1.f / 3628800.f, 1.f / 39916800.f, 1.f / 479001600.f,
                          1.f / 6.2270208e9f, 1.f / 8.71782912e10f,
                          1.f / 1.307674368e12f, 1.f / 2.0922789888e13f};

  // ---- 1-norm of dt*A -> scaling exponent s ----
  {
    const int j = tid & 63, ch = tid >> 6;
    float p = 0.f;
#pragma unroll
    for (int ii = 0; ii < 4; ++ii) p += fabsf(A[(ch * 4 + ii) * 64 + j]);
    vscr[ch * 64 + j] = p;
    __syncthreads();
    if (tid < 64) {
      float cs = 0.f;
#pragma unroll
      for (int c = 0; c < 16; ++c) cs += vscr[c * 64 + tid];
      cs *= dt;
#pragma unroll
      for (int off = 32; off > 0; off >>= 1) cs = fmaxf(cs, __shfl_xor(cs, off));
      if (tid == 0) {
        int s = 0;
        while (cs > 1.0f && s < 24) { cs *= 0.5f; ++s; }
        s_s = s;
      }
    }
    __syncthreads();
  }
  const int sq = s_s;
  const float scl = ldexpf(dt, -sq);

  // ---- X = dt*A/2^s -> M0 (LDS) and gX (global) ----
#pragma unroll
  for (int ii = 0; ii < 4; ++ii) {
    const int e = tid + NT * ii;
    const float x = A[e] * scl;
    M0[e] = x;
    gX[e] = x;
  }
  __syncthreads();

  // ---- g = phi1(X)*B, Taylor (15 matvecs, X in LDS) ----
  if (tid < 64) { va0[tid] = Bv[tid]; vg[tid] = Bv[tid]; }
  __syncthreads();
  {
    float* vin = va0;
    float* vout = vb0;
    for (int k = 1; k <= 15; ++k) {
      mv64row(M0, vin, vout, vscr);
      if (tid < 64) vg[tid] = fmaf(vout[tid], invf[k + 1], vg[tid]);
      float* t = vin; vin = vout; vout = t;
    }
  }

  // ---- e^X, Taylor-15 Paterson-Stockmeyer ----
  mm64(M0, M0, M1);  // X2
#pragma unroll
  for (int ii = 0; ii < 4; ++ii) { const int e = tid + NT * ii; gX2[e] = M1[e]; }
  mm64(M1, M0, M2);  // X3
#pragma unroll
  for (int ii = 0; ii < 4; ++ii) { const int e = tid + NT * ii; gX3[e] = M2[e]; }
  mm64(M1, M1, M0);  // X4 (X dead in LDS; gX holds copy)
  buildG(M1, gX, gX2, gX3, invf[12], invf[13], invf[14], invf[15], false);
  mm64(M1, M0, M2);
  buildG(M2, gX, gX2, gX3, invf[8], invf[9], invf[10], invf[11], true);
  mm64(M2, M0, M1);
  buildG(M1, gX, gX2, gX3, invf[4], invf[5], invf[6], invf[7], true);
  mm64(M1, M0, M2);
  buildG(M2, gX, gX2, gX3, invf[0], invf[1], invf[2], invf[3], true);

  // ---- squarings with phi1 doubling: g <- (F+I)g/2 ----
  float* Fb = M2;
  float* Fo = M1;
  for (int it = 0; it < sq; ++it) {
    mv64row(Fb, vg, va0, vscr);
    if (tid < 64) vg[tid] = 0.5f * (va0[tid] + vg[tid]);
    mm64(Fb, Fb, Fo);
    float* t = Fb; Fb = Fo; Fo = t;
  }
  // Fb = Abar

  // ---- BR doubling: BR[:,r] = Abar^r * bvec, bvec = dt*g ----
  float* BR = M0;
  float* Pcur = Fb;
  float* Ptmp = Fo;
  if (tid < 64) BR[tid * 64 + 0] = dt * vg[tid];
  __syncthreads();
  for (int wlog = 0; wlog < 6; ++wlog) {
    wmul(Pcur, BR, wlog);
    mm64(Pcur, Pcur, Ptmp);  // after 6: Pcur = Abar^64
    float* t = Pcur; Pcur = Ptmp; Ptmp = t;
  }
  // spill BR to global, free its buffer
#pragma unroll
  for (int ii = 0; ii < 4; ++ii) { const int e = tid + NT * ii; gBR[e] = BR[e]; }
  __syncthreads();

  // ---- Q = (Abar^64)^T into old BR buffer ----
  float* Q = BR;
#pragma unroll
  for (int ii = 0; ii < 4; ++ii) {
    const int e = tid + NT * ii;
    Q[(e & 63) * 64 + (e >> 6)] = Pcur[e];
  }
  __syncthreads();
  float* CQ = Ptmp;   // dead buffer
  float* Qt = Pcur;   // dead after transpose read

  // ---- CQ doubling: CQ[:,q] = (P64^T)^q * c   ((P^2)^T = (P^T)^2) ----
  if (tid < 64) CQ[tid * 64 + 0] = Cv[tid];
  __syncthreads();
  for (int wlog = 0; wlog < 6; ++wlog) {
    wmul(Q, CQ, wlog);
    if (wlog < 5) {
      mm64(Q, Q, Qt);
      float* t = Q; Q = Qt; Qt = t;
    }
  }

  // ---- reload BR, final k[64q+r] = sum_i CQ[i][q]*BR[i][r] ----
  float* BRL = Qt;
#pragma unroll
  for (int ii = 0; ii < 4; ++ii) { const int e = tid + NT * ii; BRL[e] = gBR[e]; }
  __syncthreads();
  {
    const int lane = tid & 63;
    const int g = tid >> 6;
    float acc0 = 0.f, acc1 = 0.f, acc2 = 0.f, acc3 = 0.f;
    for (int i = 0; i < 64; ++i) {
      const float bv = BRL[i * 64 + lane];
      acc0 = fmaf(CQ[i * 64 + g * 4 + 0], bv, acc0);
      acc1 = fmaf(CQ[i * 64 + g * 4 + 1], bv, acc1);
      acc2 = fmaf(CQ[i * 64 + g * 4 + 2], bv, acc2);
      acc3 = fmaf(CQ[i * 64 + g * 4 + 3], bv, acc3);
    }
    kout[(g * 4 + 0) * 64 + lane] = acc0;
    kout[(g * 4 + 1) * 64 + lane] = acc1;
    kout[(g * 4 + 2) * 64 + lane] = acc2;
    kout[(g * 4 + 3) * 64 + lane] = acc3;
  }
}

__global__ __launch_bounds__(256) void s4_conv_bcast(const float* __restrict__ ws,
                                                     const float* __restrict__ Dp,
                                                     float* __restrict__ out) {
  // 256 blocks: b = bid>>6, m = bid&63. Wave w handles t = (m*4+w) + 256*i.
  __shared__ __align__(16) float ku[4096];
  __shared__ __align__(16) float uu[4096];
  const int b = blockIdx.x >> 6;
  const int m = blockIdx.x & 63;
  for (int i = threadIdx.x; i < 1024; i += 256) {
    ((float4*)ku)[i] = ((const float4*)ws)[i];
    ((float4*)uu)[i] = ((const float4*)(ws + 4096 + b * 4096))[i];
  }
  __syncthreads();
  const float dsc = Dp[0];
  const int wv = threadIdx.x >> 6;
  const int lane = threadIdx.x & 63;
  const int c = m * 4 + wv;  // 0..255
#pragma unroll 1
  for (int i = 0; i < 16; ++i) {
    const int t = c + 256 * i;
    float acc = 0.f;
    for (int j = lane; j <= t; j += 64) acc = fmaf(ku[j], uu[t - j], acc);
#pragma unroll
    for (int off = 32; off > 0; off >>= 1) acc += __shfl_xor(acc, off);
    const float y = fmaf(dsc, uu[t], acc);
    const float4 y4 = make_float4(y, y, y, y);
    float4* dst = (float4*)(out + (size_t)(b * 4096 + t) * 1024);
#pragma unroll
    for (int rep = 0; rep < 4; ++rep) dst[lane + 64 * rep] = y4;
  }
}

extern "C" void kernel_launch(void* const* d_in, const int* in_sizes, int n_in,
                              void* d_out, int out_size, void* d_ws, size_t ws_size,
                              hipStream_t stream) {
  const float* u  = (const float*)d_in[0];
  const float* A  = (const float*)d_in[1];
  const float* B  = (const float*)d_in[2];
  const float* C  = (const float*)d_in[3];
  const float* D  = (const float*)d_in[4];
  const float* ld = (const float*)d_in[5];
  float* ws = (float*)d_ws;  // needs >= 147456 bytes

  s4_setup_ext<<<17, NT, 0, stream>>>(u, A, B, C, ld, ws);
  s4_conv_bcast<<<256, 256, 0, stream>>>(ws, D, (float*)d_out);
}

// Round 3
// 200.294 us; speedup vs baseline: 1.4620x; 1.1971x over previous
//
#include <hip/hip_runtime.h>

// S4 -> causal conv. k[j] = c^T Abar^j bbar via:
//  Abar = expm(dt*A): scale(θ=2)+Taylor-15 Paterson-Stockmeyer+square
//  bbar = dt*phi1 doubling;  k[64q+r] = (CQ^T BR)[q][r]
//  BR/CQ: 15 matvecs (cols 0..16) + MFMA widening with Abar^16/^32 (resp. transposed
//  powers of Abar^64).  All 64x64 matmuls: bf16 hi/lo split -> v_mfma_f32_16x16x32_bf16.
// Masters: fp32, global ws, pitch 68.  ws floats:
//  [0,4096) k | [4096, 4096+8*4352) masters M0..M7 | [38912, 55296) u0  (221184 B)

#define NT 1024
#define MP 68
#define MSZ (64 * MP)
#define MOFF 4096
#define U0OFF (4096 + 8 * MSZ)

typedef __attribute__((ext_vector_type(8))) short v8s;
typedef __attribute__((ext_vector_type(4))) float v4f;

__device__ __forceinline__ unsigned short bf16r(float x) {
  union { float f; unsigned u; } v; v.f = x;
  unsigned r = v.u + 0x7fffu + ((v.u >> 16) & 1u);
  return (unsigned short)(r >> 16);
}
__device__ __forceinline__ float bf2f(unsigned short h) {
  union { unsigned u; float f; } v; v.u = ((unsigned)h) << 16;
  return v.f;
}

// C[row][col] = sum_k Aop[row][k] * B[k][col]; Aop = gA or gA^T (aT).
// Writes C cols [colbase, colbase + 16*nct) from B cols [0, 16*nct).
// FRAG: [0,4096) A-hi [4096,8192) A-lo [8192,12288) B-hi [12288,16384) B-lo
__device__ void mm_mfma(const float* gA, int aT, const float* gB, float* gC,
                        int pc, int nct, int colbase, unsigned short* FRAG) {
  const int t = threadIdx.x;
  __syncthreads();
  {
    const int slot = t >> 1;            // 512 slots = Ti(4) x q(2) x lane(64)
    const int jh = (t & 1) * 4;
    const int l = slot & 63;
    const int Tq = slot >> 6;
    const int mrow = (Tq >> 1) * 16 + (l & 15);          // row (A) / col n (B)
    const int kk = (Tq & 1) * 32 + (l >> 4) * 8 + jh;    // k index
    float x0, x1, x2, x3;
    if (!aT) {
      const float4 f = *(const float4*)(gA + mrow * MP + kk);
      x0 = f.x; x1 = f.y; x2 = f.z; x3 = f.w;
    } else {
      x0 = gA[(kk + 0) * MP + mrow]; x1 = gA[(kk + 1) * MP + mrow];
      x2 = gA[(kk + 2) * MP + mrow]; x3 = gA[(kk + 3) * MP + mrow];
    }
    unsigned short h0 = bf16r(x0), h1 = bf16r(x1), h2 = bf16r(x2), h3 = bf16r(x3);
    ushort4 H, L;
    H.x = h0; H.y = h1; H.z = h2; H.w = h3;
    L.x = bf16r(x0 - bf2f(h0)); L.y = bf16r(x1 - bf2f(h1));
    L.z = bf16r(x2 - bf2f(h2)); L.w = bf16r(x3 - bf2f(h3));
    *(ushort4*)(FRAG + slot * 8 + jh) = H;
    *(ushort4*)(FRAG + 4096 + slot * 8 + jh) = L;
    const float y0 = gB[(kk + 0) * MP + mrow], y1 = gB[(kk + 1) * MP + mrow];
    const float y2 = gB[(kk + 2) * MP + mrow], y3 = gB[(kk + 3) * MP + mrow];
    unsigned short g0 = bf16r(y0), g1 = bf16r(y1), g2 = bf16r(y2), g3 = bf16r(y3);
    H.x = g0; H.y = g1; H.z = g2; H.w = g3;
    L.x = bf16r(y0 - bf2f(g0)); L.y = bf16r(y1 - bf2f(g1));
    L.z = bf16r(y2 - bf2f(g2)); L.w = bf16r(y3 - bf2f(g3));
    *(ushort4*)(FRAG + 8192 + slot * 8 + jh) = H;
    *(ushort4*)(FRAG + 12288 + slot * 8 + jh) = L;
  }
  __syncthreads();
  {
    const int w = t >> 6, l = t & 63;
    const int R = w >> 2, Cc = w & 3;
    if (Cc < nct) {
      const v8s Ah0 = *(const v8s*)(FRAG + ((R * 2 + 0) * 64 + l) * 8);
      const v8s Ah1 = *(const v8s*)(FRAG + ((R * 2 + 1) * 64 + l) * 8);
      const v8s Al0 = *(const v8s*)(FRAG + 4096 + ((R * 2 + 0) * 64 + l) * 8);
      const v8s Al1 = *(const v8s*)(FRAG + 4096 + ((R * 2 + 1) * 64 + l) * 8);
      const v8s Bh0 = *(const v8s*)(FRAG + 8192 + ((Cc * 2 + 0) * 64 + l) * 8);
      const v8s Bh1 = *(const v8s*)(FRAG + 8192 + ((Cc * 2 + 1) * 64 + l) * 8);
      const v8s Bl0 = *(const v8s*)(FRAG + 12288 + ((Cc * 2 + 0) * 64 + l) * 8);
      const v8s Bl1 = *(const v8s*)(FRAG + 12288 + ((Cc * 2 + 1) * 64 + l) * 8);
      v4f acc = {0.f, 0.f, 0.f, 0.f};
      acc = __builtin_amdgcn_mfma_f32_16x16x32_bf16(Ah0, Bh0, acc, 0, 0, 0);
      acc = __builtin_amdgcn_mfma_f32_16x16x32_bf16(Ah1, Bh1, acc, 0, 0, 0);
      acc = __builtin_amdgcn_mfma_f32_16x16x32_bf16(Ah0, Bl0, acc, 0, 0, 0);
      acc = __builtin_amdgcn_mfma_f32_16x16x32_bf16(Ah1, Bl1, acc, 0, 0, 0);
      acc = __builtin_amdgcn_mfma_f32_16x16x32_bf16(Al0, Bh0, acc, 0, 0, 0);
      acc = __builtin_amdgcn_mfma_f32_16x16x32_bf16(Al1, Bh1, acc, 0, 0, 0);
      const int col = colbase + Cc * 16 + (l & 15);
      const int r0 = R * 16 + (l >> 4) * 4;
      gC[(r0 + 0) * pc + col] = acc[0];
      gC[(r0 + 1) * pc + col] = acc[1];
      gC[(r0 + 2) * pc + col] = acc[2];
      gC[(r0 + 3) * pc + col] = acc[3];
    }
  }
  __syncthreads();
}

// vout = M * vin (row dots); M pitch MP (global or LDS via generic ptr).
__device__ __forceinline__ void mv64(const float* Mm, const float* vin,
                                     float* vout, float* vscr) {
  __syncthreads();
  const int t = threadIdx.x, i = t & 63, c = t >> 6;
  const float4 m = *(const float4*)(Mm + i * MP + c * 4);
  vscr[t] = fmaf(m.x, vin[c * 4 + 0], fmaf(m.y, vin[c * 4 + 1],
            fmaf(m.z, vin[c * 4 + 2], m.w * vin[c * 4 + 3])));
  __syncthreads();
  if (t < 64) {
    float s = 0.f;
#pragma unroll
    for (int cc = 0; cc < 16; ++cc) s += vscr[cc * 64 + t];
    vout[t] = s;
  }
  __syncthreads();
}

__device__ void buildC(float* dst, const float* X, const float* X2, const float* X3,
                       float c0, float c1, float c2, float c3, int add) {
  __syncthreads();
  for (int e = threadIdx.x; e < 64 * MP; e += NT) {
    const int r = e / MP, c = e - r * MP;
    if (c < 64) {
      float v = c1 * X[e] + c2 * X2[e] + c3 * X3[e];
      if (c == r) v += c0;
      dst[e] = add ? dst[e] + v : v;
    }
  }
  __syncthreads();
}

__device__ __forceinline__ void ldscache(float* Lc, const float* gM) {
  __syncthreads();
  const int t = threadIdx.x;
  const int r = t >> 4, c4 = (t & 15) * 4;
  *(float4*)(Lc + r * MP + c4) = *(const float4*)(gM + r * MP + c4);
  __syncthreads();
}

__global__ __launch_bounds__(NT) void s4_setup(const float* __restrict__ u,
    const float* __restrict__ A, const float* __restrict__ Bv,
    const float* __restrict__ Cv, const float* __restrict__ logdt,
    float* __restrict__ ws) {
  if (blockIdx.x > 0) {
    const int idx = (blockIdx.x - 1) * NT + threadIdx.x;  // 0..16383
    ws[U0OFF + idx] = u[(size_t)idx * 1024];
    return;
  }
  __shared__ __align__(16) unsigned short FRAG[16384];
  __shared__ float vscr[NT];
  __shared__ float va[64], vb[64], vg[64];
  __shared__ int s_s;
  float* Xc = (float*)FRAG;  // 4352 floats fit in 8192

  const int t = threadIdx.x;
  float* kbuf = ws;
  float* M0 = ws + MOFF;          float* M1 = M0 + MSZ;
  float* M2 = M1 + MSZ;           float* M3 = M2 + MSZ;
  float* M4 = M3 + MSZ;           float* M5 = M4 + MSZ;
  float* M6 = M5 + MSZ;           float* M7 = M6 + MSZ;
  const float dt = expf(logdt[0]);

  const float invf[17] = {1.f, 1.f, 1.f / 2.f, 1.f / 6.f, 1.f / 24.f, 1.f / 120.f,
                          1.f / 720.f, 1.f / 5040.f, 1.f / 40320.f, 1.f / 362880.f,
                          1.f / 3628800.f, 1.f / 39916800.f, 1.f / 479001600.f,
                          1.f / 6.2270208e9f, 1.f / 8.71782912e10f,
                          1.f / 1.307674368e12f, 1.f / 2.0922789888e13f};

  // ---- 1-norm of dt*A -> s (theta = 2.0) ----
  {
    const int j = t & 63, ch = t >> 6;
    float p = 0.f;
#pragma unroll
    for (int ii = 0; ii < 4; ++ii) p += fabsf(A[(ch * 4 + ii) * 64 + j]);
    vscr[t] = p;
    __syncthreads();
    if (t < 64) {
      float cs = 0.f;
#pragma unroll
      for (int c = 0; c < 16; ++c) cs += vscr[c * 64 + t];
      cs *= dt;
#pragma unroll
      for (int off = 32; off > 0; off >>= 1) cs = fmaxf(cs, __shfl_xor(cs, off));
      if (t == 0) {
        int s = 0;
        while (cs > 2.0f && s < 30) { cs *= 0.5f; ++s; }
        s_s = s;
      }
    }
    __syncthreads();
  }
  const int sq = s_s;
  const float scl = ldexpf(dt, -sq);

  // ---- X master (M0) + LDS cache ----
  {
    const float4 a4 = *(const float4*)(A + t * 4);
    float4 x;
    x.x = a4.x * scl; x.y = a4.y * scl; x.z = a4.z * scl; x.w = a4.w * scl;
    const int r = t >> 4, c4 = (t & 15) * 4;
    *(float4*)(M0 + r * MP + c4) = x;
    *(float4*)(Xc + r * MP + c4) = x;
  }
  __syncthreads();

  // ---- g = phi1(X)*B (15 matvecs on LDS X) ----
  if (t < 64) { va[t] = Bv[t]; vg[t] = Bv[t]; }
  {
    float* vc = va; float* vn = vb;
    for (int k = 1; k <= 15; ++k) {
      mv64(Xc, vc, vn, vscr);
      if (t < 64) vg[t] = fmaf(vn[t], invf[k + 1], vg[t]);
      float* tmp = vc; vc = vn; vn = tmp;
    }
    __syncthreads();
  }

  // ---- e^X: Taylor-15 Paterson-Stockmeyer ----
  mm_mfma(M0, 0, M0, M1, MP, 4, 0, FRAG);   // X2
  mm_mfma(M1, 0, M0, M2, MP, 4, 0, FRAG);   // X3
  mm_mfma(M1, 0, M1, M3, MP, 4, 0, FRAG);   // X4
  buildC(M5, M0, M1, M2, invf[12], invf[13], invf[14], invf[15], 0);
  mm_mfma(M5, 0, M3, M4, MP, 4, 0, FRAG);
  buildC(M4, M0, M1, M2, invf[8], invf[9], invf[10], invf[11], 1);
  mm_mfma(M4, 0, M3, M5, MP, 4, 0, FRAG);
  buildC(M5, M0, M1, M2, invf[4], invf[5], invf[6], invf[7], 1);
  mm_mfma(M5, 0, M3, M4, MP, 4, 0, FRAG);
  buildC(M4, M0, M1, M2, invf[0], invf[1], invf[2], invf[3], 1);  // M4 = e^X

  // ---- squarings + phi1 doubling ----
  float* F = M4; float* Fo = M5;
  for (int it = 0; it < sq; ++it) {
    mv64(F, vg, va, vscr);
    if (t < 64) vg[t] = 0.5f * (va[t] + vg[t]);
    mm_mfma(F, 0, F, Fo, MP, 4, 0, FRAG);
    float* tmp = F; F = Fo; Fo = tmp;
  }
  // F = Abar

  // ---- BR cols 0..16: bvec then 15 matvecs (Abar cached in LDS) ----
  ldscache(Xc, F);
  if (t < 64) { va[t] = dt * vg[t]; M6[t * MP + 0] = dt * vg[t]; }
  __syncthreads();
  {
    float* vc = va; float* vn = vb;
    for (int r = 1; r < 16; ++r) {
      mv64(Xc, vc, vn, vscr);
      if (t < 64) M6[t * MP + r] = vn[t];
      float* tmp = vc; vc = vn; vn = tmp;
    }
    __syncthreads();
  }

  // ---- power chain + BR widening ----
  mm_mfma(F, 0, F, M0, MP, 4, 0, FRAG);     // P2
  mm_mfma(M0, 0, M0, M1, MP, 4, 0, FRAG);   // P4
  mm_mfma(M1, 0, M1, M0, MP, 4, 0, FRAG);   // P8
  mm_mfma(M0, 0, M0, M1, MP, 4, 0, FRAG);   // P16
  mm_mfma(M1, 0, M6, M6, MP, 1, 16, FRAG);  // BR[:,16:32) = P16*BR[:,0:16)
  mm_mfma(M1, 0, M1, M0, MP, 4, 0, FRAG);   // P32
  mm_mfma(M0, 0, M6, M6, MP, 2, 32, FRAG);  // BR[:,32:64) = P32*BR[:,0:32)
  mm_mfma(M0, 0, M0, M1, MP, 4, 0, FRAG);   // P64 @ M1

  // ---- CQ cols 0..16: Q = P64^T cached transposed in LDS ----
  __syncthreads();
  for (int e = t; e < 4096; e += NT) {
    const int r = e >> 6, c = e & 63;
    Xc[c * MP + r] = M1[r * MP + c];
  }
  __syncthreads();
  if (t < 64) { va[t] = Cv[t]; M7[t * MP + 0] = Cv[t]; }
  __syncthreads();
  {
    float* vc = va; float* vn = vb;
    for (int q = 1; q < 16; ++q) {
      mv64(Xc, vc, vn, vscr);
      if (t < 64) M7[t * MP + q] = vn[t];
      float* tmp = vc; vc = vn; vn = tmp;
    }
    __syncthreads();
  }

  // ---- squarings of P64 + CQ widening (transposed A-operand) ----
  mm_mfma(M1, 0, M1, M0, MP, 4, 0, FRAG);   // A^128
  mm_mfma(M0, 0, M0, M2, MP, 4, 0, FRAG);   // A^256
  mm_mfma(M2, 0, M2, M0, MP, 4, 0, FRAG);   // A^512
  mm_mfma(M0, 0, M0, M2, MP, 4, 0, FRAG);   // A^1024 @ M2
  mm_mfma(M2, 1, M7, M7, MP, 1, 16, FRAG);  // CQ[:,16:32) = (A^1024)^T CQ[:,0:16)
  mm_mfma(M2, 0, M2, M0, MP, 4, 0, FRAG);   // A^2048 @ M0
  mm_mfma(M0, 1, M7, M7, MP, 2, 32, FRAG);  // CQ[:,32:64)

  // ---- k[64q+r] = sum_i CQ[i][q] * BR[i][r] ----
  mm_mfma(M7, 1, M6, kbuf, 64, 4, 0, FRAG);
}

__global__ __launch_bounds__(256) void s4_conv(const float* __restrict__ ws,
                                               const float* __restrict__ Dp,
                                               float* __restrict__ out) {
  __shared__ __align__(16) float ku[4096];
  __shared__ __align__(16) float uu[4096];
  const int b = blockIdx.x >> 6, m = blockIdx.x & 63;
  for (int i = threadIdx.x; i < 1024; i += 256) {
    ((float4*)ku)[i] = ((const float4*)ws)[i];
    ((float4*)uu)[i] = ((const float4*)(ws + U0OFF + b * 4096))[i];
  }
  __syncthreads();
  const float dsc = Dp[0];
  const int wv = threadIdx.x >> 6, lane = threadIdx.x & 63;
  const int c = m * 4 + wv;
#pragma unroll 1
  for (int i = 0; i < 16; ++i) {
    const int tt = c + 256 * i;
    float acc = 0.f;
    for (int j = lane; j <= tt; j += 64) acc = fmaf(ku[j], uu[tt - j], acc);
#pragma unroll
    for (int off = 32; off > 0; off >>= 1) acc += __shfl_xor(acc, off);
    if (lane == 0) out[(size_t)(b * 4096 + tt) * 1024] = acc + dsc * uu[tt];
  }
}

__global__ __launch_bounds__(256) void s4_bcast(float* __restrict__ out) {
  __shared__ float sy[4];
  const int row0 = blockIdx.x * 4;
  if (threadIdx.x < 4) sy[threadIdx.x] = out[(size_t)(row0 + threadIdx.x) * 1024];
  __syncthreads();
  const int i = threadIdx.x >> 6, l = threadIdx.x & 63;
  const float y = sy[i];
  const float4 y4 = make_float4(y, y, y, y);
  float4* dst = (float4*)(out + (size_t)(row0 + i) * 1024);
  dst[l] = y4; dst[l + 64] = y4; dst[l + 128] = y4; dst[l + 192] = y4;
}

extern "C" void kernel_launch(void* const* d_in, const int* in_sizes, int n_in,
                              void* d_out, int out_size, void* d_ws, size_t ws_size,
                              hipStream_t stream) {
  const float* u  = (const float*)d_in[0];
  const float* A  = (const float*)d_in[1];
  const float* B  = (const float*)d_in[2];
  const float* C  = (const float*)d_in[3];
  const float* D  = (const float*)d_in[4];
  const float* ld = (const float*)d_in[5];
  float* ws = (float*)d_ws;  // needs >= 221184 bytes

  s4_setup<<<17, NT, 0, stream>>>(u, A, B, C, ld, ws);
  s4_conv<<<256, 256, 0, stream>>>(ws, D, (float*)d_out);
  s4_bcast<<<4096, 256, 0, stream>>>((float*)d_out);
}

// Round 5
// 182.204 us; speedup vs baseline: 1.6072x; 1.0993x over previous
//
#include <hip/hip_runtime.h>

// S4 -> causal conv. k[j] = c^T Abar^j bbar via:
//  Abar = expm(dt*A): scale(θ=2)+Taylor-15 Paterson-Stockmeyer+square
//  bbar = dt*phi1 doubling;  k[64q+r] = (CQ^T BR)[q][r]
//  BR/CQ: 15 matvecs (cols 0..16) + MFMA widening with Abar^16/^32 (resp. transposed
//  powers of Abar^64).  All 64x64 matmuls: bf16 hi/lo split -> v_mfma_f32_16x16x32_bf16.
// Masters: fp32, global ws, pitch 68.  ws floats:
//  [0,4096) k | [4096, 4096+8*4352) masters M0..M7 | [38912, 55296) u0  (221184 B)

#define NT 1024
#define MP 68
#define MSZ (64 * MP)
#define MOFF 4096
#define U0OFF (4096 + 8 * MSZ)

typedef __attribute__((ext_vector_type(8))) short v8s;
typedef __attribute__((ext_vector_type(4))) float v4f;

__device__ __forceinline__ unsigned short bf16r(float x) {
  union { float f; unsigned u; } v; v.f = x;
  unsigned r = v.u + 0x7fffu + ((v.u >> 16) & 1u);
  return (unsigned short)(r >> 16);
}
__device__ __forceinline__ float bf2f(unsigned short h) {
  union { unsigned u; float f; } v; v.u = ((unsigned)h) << 16;
  return v.f;
}

// C[row][col] = sum_k Aop[row][k] * B[k][col]; Aop = gA or gA^T (aT).
// Writes C cols [colbase, colbase + 16*nct) from B cols [0, 16*nct).
// FRAG: [0,4096) A-hi [4096,8192) A-lo [8192,12288) B-hi [12288,16384) B-lo
__device__ void mm_mfma(const float* gA, int aT, const float* gB, float* gC,
                        int pc, int nct, int colbase, unsigned short* FRAG) {
  const int t = threadIdx.x;
  __syncthreads();
  {
    const int slot = t >> 1;            // 512 slots = Ti(4) x q(2) x lane(64)
    const int jh = (t & 1) * 4;
    const int l = slot & 63;
    const int Tq = slot >> 6;
    const int mrow = (Tq >> 1) * 16 + (l & 15);          // row (A) / col n (B)
    const int kk = (Tq & 1) * 32 + (l >> 4) * 8 + jh;    // k index
    float x0, x1, x2, x3;
    if (!aT) {
      const float4 f = *(const float4*)(gA + mrow * MP + kk);
      x0 = f.x; x1 = f.y; x2 = f.z; x3 = f.w;
    } else {
      x0 = gA[(kk + 0) * MP + mrow]; x1 = gA[(kk + 1) * MP + mrow];
      x2 = gA[(kk + 2) * MP + mrow]; x3 = gA[(kk + 3) * MP + mrow];
    }
    unsigned short h0 = bf16r(x0), h1 = bf16r(x1), h2 = bf16r(x2), h3 = bf16r(x3);
    ushort4 H, L;
    H.x = h0; H.y = h1; H.z = h2; H.w = h3;
    L.x = bf16r(x0 - bf2f(h0)); L.y = bf16r(x1 - bf2f(h1));
    L.z = bf16r(x2 - bf2f(h2)); L.w = bf16r(x3 - bf2f(h3));
    *(ushort4*)(FRAG + slot * 8 + jh) = H;
    *(ushort4*)(FRAG + 4096 + slot * 8 + jh) = L;
    const float y0 = gB[(kk + 0) * MP + mrow], y1 = gB[(kk + 1) * MP + mrow];
    const float y2 = gB[(kk + 2) * MP + mrow], y3 = gB[(kk + 3) * MP + mrow];
    unsigned short g0 = bf16r(y0), g1 = bf16r(y1), g2 = bf16r(y2), g3 = bf16r(y3);
    H.x = g0; H.y = g1; H.z = g2; H.w = g3;
    L.x = bf16r(y0 - bf2f(g0)); L.y = bf16r(y1 - bf2f(g1));
    L.z = bf16r(y2 - bf2f(g2)); L.w = bf16r(y3 - bf2f(g3));
    *(ushort4*)(FRAG + 8192 + slot * 8 + jh) = H;
    *(ushort4*)(FRAG + 12288 + slot * 8 + jh) = L;
  }
  __syncthreads();
  {
    const int w = t >> 6, l = t & 63;
    const int R = w >> 2, Cc = w & 3;
    if (Cc < nct) {
      const v8s Ah0 = *(const v8s*)(FRAG + ((R * 2 + 0) * 64 + l) * 8);
      const v8s Ah1 = *(const v8s*)(FRAG + ((R * 2 + 1) * 64 + l) * 8);
      const v8s Al0 = *(const v8s*)(FRAG + 4096 + ((R * 2 + 0) * 64 + l) * 8);
      const v8s Al1 = *(const v8s*)(FRAG + 4096 + ((R * 2 + 1) * 64 + l) * 8);
      const v8s Bh0 = *(const v8s*)(FRAG + 8192 + ((Cc * 2 + 0) * 64 + l) * 8);
      const v8s Bh1 = *(const v8s*)(FRAG + 8192 + ((Cc * 2 + 1) * 64 + l) * 8);
      const v8s Bl0 = *(const v8s*)(FRAG + 12288 + ((Cc * 2 + 0) * 64 + l) * 8);
      const v8s Bl1 = *(const v8s*)(FRAG + 12288 + ((Cc * 2 + 1) * 64 + l) * 8);
      v4f acc = {0.f, 0.f, 0.f, 0.f};
      acc = __builtin_amdgcn_mfma_f32_16x16x32_bf16(Ah0, Bh0, acc, 0, 0, 0);
      acc = __builtin_amdgcn_mfma_f32_16x16x32_bf16(Ah1, Bh1, acc, 0, 0, 0);
      acc = __builtin_amdgcn_mfma_f32_16x16x32_bf16(Ah0, Bl0, acc, 0, 0, 0);
      acc = __builtin_amdgcn_mfma_f32_16x16x32_bf16(Ah1, Bl1, acc, 0, 0, 0);
      acc = __builtin_amdgcn_mfma_f32_16x16x32_bf16(Al0, Bh0, acc, 0, 0, 0);
      acc = __builtin_amdgcn_mfma_f32_16x16x32_bf16(Al1, Bh1, acc, 0, 0, 0);
      const int col = colbase + Cc * 16 + (l & 15);
      const int r0 = R * 16 + (l >> 4) * 4;
      gC[(r0 + 0) * pc + col] = acc[0];
      gC[(r0 + 1) * pc + col] = acc[1];
      gC[(r0 + 2) * pc + col] = acc[2];
      gC[(r0 + 3) * pc + col] = acc[3];
    }
  }
  __syncthreads();
}

// vout = M*vin (row dots), M row-major with pitch MP (LDS or global).
__device__ __forceinline__ void mv64(const float* Mm, const float* vin,
                                     float* vout, float* vscr) {
  __syncthreads();
  const int t = threadIdx.x, i = t & 63, c = t >> 6;
  const float4 m = *(const float4*)(Mm + i * MP + c * 4);
  vscr[t] = fmaf(m.x, vin[c * 4 + 0], fmaf(m.y, vin[c * 4 + 1],
            fmaf(m.z, vin[c * 4 + 2], m.w * vin[c * 4 + 3])));
  __syncthreads();
  if (t < 64) {
    float s = 0.f;
#pragma unroll
    for (int cc = 0; cc < 16; ++cc) s += vscr[cc * 64 + t];
    vout[t] = s;
  }
  __syncthreads();
}

__device__ void buildC(float* dst, const float* X, const float* X2, const float* X3,
                       float c0, float c1, float c2, float c3, int add) {
  __syncthreads();
  for (int e = threadIdx.x; e < 64 * MP; e += NT) {
    const int r = e / MP, c = e - r * MP;
    if (c < 64) {
      float v = c1 * X[e] + c2 * X2[e] + c3 * X3[e];
      if (c == r) v += c0;
      dst[e] = add ? dst[e] + v : v;
    }
  }
  __syncthreads();
}

__global__ __launch_bounds__(NT) void s4_setup(const float* __restrict__ u,
    const float* __restrict__ A, const float* __restrict__ Bv,
    const float* __restrict__ Cv, const float* __restrict__ logdt,
    float* __restrict__ ws) {
  if (blockIdx.x > 0) {
    const int idx = (blockIdx.x - 1) * NT + threadIdx.x;  // 0..16383
    ws[U0OFF + idx] = u[(size_t)idx * 1024];
    return;
  }
  __shared__ __align__(16) unsigned short FRAG[16384];
  __shared__ float vscr[NT];
  __shared__ float va[64], vb[64], vg[64];
  __shared__ int s_s;
  float* Xc = (float*)FRAG;  // 4352 floats fit in 8192

  const int t = threadIdx.x;
  float* kbuf = ws;
  float* M0 = ws + MOFF;          float* M1 = M0 + MSZ;
  float* M2 = M1 + MSZ;           float* M3 = M2 + MSZ;
  float* M4 = M3 + MSZ;           float* M5 = M4 + MSZ;
  float* M6 = M5 + MSZ;           float* M7 = M6 + MSZ;
  const float dt = expf(logdt[0]);

  const float invf[17] = {1.f, 1.f, 1.f / 2.f, 1.f / 6.f, 1.f / 24.f, 1.f / 120.f,
                          1.f / 720.f, 1.f / 5040.f, 1.f / 40320.f, 1.f / 362880.f,
                          1.f / 3628800.f, 1.f / 39916800.f, 1.f / 479001600.f,
                          1.f / 6.2270208e9f, 1.f / 8.71782912e10f,
                          1.f / 1.307674368e12f, 1.f / 2.0922789888e13f};

  // ---- 1-norm of dt*A -> s (theta = 2.0) ----
  {
    const int j = t & 63, ch = t >> 6;
    float p = 0.f;
#pragma unroll
    for (int ii = 0; ii < 4; ++ii) p += fabsf(A[(ch * 4 + ii) * 64 + j]);
    vscr[t] = p;
    __syncthreads();
    if (t < 64) {
      float cs = 0.f;
#pragma unroll
      for (int c = 0; c < 16; ++c) cs += vscr[c * 64 + t];
      cs *= dt;
#pragma unroll
      for (int off = 32; off > 0; off >>= 1) cs = fmaxf(cs, __shfl_xor(cs, off));
      if (t == 0) {
        int s = 0;
        while (cs > 2.0f && s < 30) { cs *= 0.5f; ++s; }
        s_s = s;
      }
    }
    __syncthreads();
  }
  const int sq = s_s;
  const float scl = ldexpf(dt, -sq);

  // ---- X master (M0) + LDS cache ----
  {
    const float4 a4 = *(const float4*)(A + t * 4);
    float4 x;
    x.x = a4.x * scl; x.y = a4.y * scl; x.z = a4.z * scl; x.w = a4.w * scl;
    const int r = t >> 4, c4 = (t & 15) * 4;
    *(float4*)(M0 + r * MP + c4) = x;
    *(float4*)(Xc + r * MP + c4) = x;
  }
  __syncthreads();

  // ---- g = phi1(X)*B (15 matvecs on LDS X) ----
  if (t < 64) { va[t] = Bv[t]; vg[t] = Bv[t]; }
  {
    float* vc = va; float* vn = vb;
    for (int k = 1; k <= 15; ++k) {
      mv64(Xc, vc, vn, vscr);
      if (t < 64) vg[t] = fmaf(vn[t], invf[k + 1], vg[t]);
      float* tmp = vc; vc = vn; vn = tmp;
    }
    __syncthreads();
  }

  // ---- e^X: Taylor-15 Paterson-Stockmeyer ----
  mm_mfma(M0, 0, M0, M1, MP, 4, 0, FRAG);   // X2
  mm_mfma(M1, 0, M0, M2, MP, 4, 0, FRAG);   // X3
  mm_mfma(M1, 0, M1, M3, MP, 4, 0, FRAG);   // X4
  buildC(M5, M0, M1, M2, invf[12], invf[13], invf[14], invf[15], 0);
  mm_mfma(M5, 0, M3, M4, MP, 4, 0, FRAG);
  buildC(M4, M0, M1, M2, invf[8], invf[9], invf[10], invf[11], 1);
  mm_mfma(M4, 0, M3, M5, MP, 4, 0, FRAG);
  buildC(M5, M0, M1, M2, invf[4], invf[5], invf[6], invf[7], 1);
  mm_mfma(M5, 0, M3, M4, MP, 4, 0, FRAG);
  buildC(M4, M0, M1, M2, invf[0], invf[1], invf[2], invf[3], 1);  // M4 = e^X

  // ---- squarings + phi1 doubling ----
  float* F = M4; float* Fo = M5;
  for (int it = 0; it < sq; ++it) {
    mv64(F, vg, va, vscr);
    if (t < 64) vg[t] = 0.5f * (va[t] + vg[t]);
    mm_mfma(F, 0, F, Fo, MP, 4, 0, FRAG);
    float* tmp = F; F = Fo; Fo = tmp;
  }
  // F = Abar

  // ---- BR cols 0..16: bvec then 15 matvecs (Abar cached in LDS) ----
  __syncthreads();
  {
    const int r = t >> 4, c4 = (t & 15) * 4;
    *(float4*)(Xc + r * MP + c4) = *(const float4*)(F + r * MP + c4);
  }
  if (t < 64) { va[t] = dt * vg[t]; M6[t * MP + 0] = dt * vg[t]; }
  __syncthreads();
  {
    float* vc = va; float* vn = vb;
    for (int r = 1; r < 16; ++r) {
      mv64(Xc, vc, vn, vscr);
      if (t < 64) M6[t * MP + r] = vn[t];
      float* tmp = vc; vc = vn; vn = tmp;
    }
    __syncthreads();
  }

  // ---- power chain + BR widening ----
  mm_mfma(F, 0, F, M0, MP, 4, 0, FRAG);     // P2
  mm_mfma(M0, 0, M0, M1, MP, 4, 0, FRAG);   // P4
  mm_mfma(M1, 0, M1, M0, MP, 4, 0, FRAG);   // P8
  mm_mfma(M0, 0, M0, M1, MP, 4, 0, FRAG);   // P16
  mm_mfma(M1, 0, M6, M6, MP, 1, 16, FRAG);  // BR[:,16:32) = P16*BR[:,0:16)
  mm_mfma(M1, 0, M1, M0, MP, 4, 0, FRAG);   // P32
  mm_mfma(M0, 0, M6, M6, MP, 2, 32, FRAG);  // BR[:,32:64)
  mm_mfma(M0, 0, M0, M1, MP, 4, 0, FRAG);   // P64 @ M1

  // ---- CQ cols 0..16: Q = P64^T cached transposed in LDS ----
  __syncthreads();
  for (int e = t; e < 4096; e += NT) {
    const int r = e >> 6, c = e & 63;
    Xc[c * MP + r] = M1[r * MP + c];
  }
  __syncthreads();
  if (t < 64) { va[t] = Cv[t]; M7[t * MP + 0] = Cv[t]; }
  __syncthreads();
  {
    float* vc = va; float* vn = vb;
    for (int q = 1; q < 16; ++q) {
      mv64(Xc, vc, vn, vscr);
      if (t < 64) M7[t * MP + q] = vn[t];
      float* tmp = vc; vc = vn; vn = tmp;
    }
    __syncthreads();
  }

  // ---- squarings of P64 + CQ widening (transposed A-operand) ----
  mm_mfma(M1, 0, M1, M0, MP, 4, 0, FRAG);   // A^128
  mm_mfma(M0, 0, M0, M2, MP, 4, 0, FRAG);   // A^256
  mm_mfma(M2, 0, M2, M0, MP, 4, 0, FRAG);   // A^512
  mm_mfma(M0, 0, M0, M2, MP, 4, 0, FRAG);   // A^1024 @ M2
  mm_mfma(M2, 1, M7, M7, MP, 1, 16, FRAG);  // CQ[:,16:32) = (A^1024)^T CQ[:,0:16)
  mm_mfma(M2, 0, M2, M0, MP, 4, 0, FRAG);   // A^2048 @ M0
  mm_mfma(M0, 1, M7, M7, MP, 2, 32, FRAG);  // CQ[:,32:64)

  // ---- k[64q+r] = sum_i CQ[i][q] * BR[i][r] ----
  mm_mfma(M7, 1, M6, kbuf, 64, 4, 0, FRAG);
}

// Fused conv + broadcast: 4096 blocks x 256 threads; block computes 4 y-scalars
// then streams 4 rows x 1024 cols of broadcast float4 stores (write-bound).
__global__ __launch_bounds__(256) void s4_out(const float* __restrict__ ws,
                                              const float* __restrict__ Dp,
                                              float* __restrict__ out) {
  const int bid = blockIdx.x;               // 4096 blocks
  const int b = bid >> 10;
  const int t0 = (bid & 1023) << 2;
  const float* kb = ws;
  const float* ub = ws + U0OFF + (b << 12);
  const int tid = threadIdx.x;
  const int t3 = t0 + 3;
  float a0 = 0.f, a1 = 0.f, a2 = 0.f, a3 = 0.f;
  for (int j = tid; j <= t3; j += 256) {
    const float kj = kb[j];
    if (j <= t0)     a0 = fmaf(kj, ub[t0 - j], a0);
    if (j <= t0 + 1) a1 = fmaf(kj, ub[t0 + 1 - j], a1);
    if (j <= t0 + 2) a2 = fmaf(kj, ub[t0 + 2 - j], a2);
    a3 = fmaf(kj, ub[t3 - j], a3);
  }
#pragma unroll
  for (int off = 32; off > 0; off >>= 1) {
    a0 += __shfl_xor(a0, off);
    a1 += __shfl_xor(a1, off);
    a2 += __shfl_xor(a2, off);
    a3 += __shfl_xor(a3, off);
  }
  __shared__ float red[4][4];
  __shared__ float sy[4];
  if ((tid & 63) == 0) {
    const int w = tid >> 6;
    red[0][w] = a0; red[1][w] = a1; red[2][w] = a2; red[3][w] = a3;
  }
  __syncthreads();
  if (tid < 4)
    sy[tid] = red[tid][0] + red[tid][1] + red[tid][2] + red[tid][3] +
              Dp[0] * ub[t0 + tid];
  __syncthreads();
  const int row = tid >> 6, l = tid & 63;
  const float y = sy[row];
  const float4 y4 = make_float4(y, y, y, y);
  float4* dst = (float4*)(out + ((size_t)(b << 12) + t0 + row) * 1024);
  dst[l] = y4; dst[l + 64] = y4; dst[l + 128] = y4; dst[l + 192] = y4;
}

extern "C" void kernel_launch(void* const* d_in, const int* in_sizes, int n_in,
                              void* d_out, int out_size, void* d_ws, size_t ws_size,
                              hipStream_t stream) {
  const float* u  = (const float*)d_in[0];
  const float* A  = (const float*)d_in[1];
  const float* B  = (const float*)d_in[2];
  const float* C  = (const float*)d_in[3];
  const float* D  = (const float*)d_in[4];
  const float* ld = (const float*)d_in[5];
  float* ws = (float*)d_ws;  // needs >= 221184 bytes

  s4_setup<<<17, NT, 0, stream>>>(u, A, B, C, ld, ws);
  s4_out<<<4096, 256, 0, stream>>>(ws, D, (float*)d_out);
}

// Round 6
// 168.972 us; speedup vs baseline: 1.7331x; 1.0783x over previous
//
#include <hip/hip_runtime.h>

// S4 -> causal conv. y[b,t] = d*u0[b,t] + sum_j k[j]*u0[b,t-j], k[j]=c^T Abar^j bbar.
// Abar = expm(dt*A): scale (theta=2) + Taylor-15 Paterson-Stockmeyer + squarings.
// bbar = dt*phi1(dtA)B: phi1 by PS on vectors + doubling through the squarings.
// k = CQ^T BR bilinear split; BR/CQ stored TRANSPOSED (BRT/CQT) so every matmul
// reads operands as rows (coalesced) or from LDS. Hot chain (all squarings) lives
// in ONE LDS slot S0, in-place: stage S0->FRAG(bf16 hi/lo), MFMA, write back.
// ws floats: [0,4096) k | [4096,20480) u0 | 20480 gX | 24832 gX2 | 29184 gX3
//            | 33536 gU0 | 37888 gU1 | 42240 gBRT | 46592 gCQT   (203776 B)

#define NT 1024
#define MP 68
#define MB (64 * MP)

typedef __attribute__((ext_vector_type(8))) short v8s;
typedef __attribute__((ext_vector_type(4))) float v4f;

__device__ __forceinline__ unsigned short bf16r(float x) {
  union { float f; unsigned u; } v; v.f = x;
  unsigned r = v.u + 0x7fffu + ((v.u >> 16) & 1u);
  return (unsigned short)(r >> 16);
}
__device__ __forceinline__ float bf2f(unsigned short h) {
  union { unsigned u; float f; } v; v.u = ((unsigned)h) << 16;
  return v.f;
}

// FRAG layout (ushorts): A-hi @0, A-lo @4096, B-hi @8192, B-lo @12288.
// C[rowbase+i][colbase+j] = sum_k A[i][k]*B[k][j], pitches MP (Cd: cpitch).
// A rows at Ag (LDS or global). B: bT=0 -> B[k][n]=Bs[k*MP+n] (column staging);
// bT=1 -> B[k][n]=Bs[n*MP+k] (row staging of B^T). Tiles: R<nrt, Cc<nct.
// In-place safe for Cd==Ag==Bs (staging completes before epilogue).
__device__ void mm(const float* Ag, const float* Bs, int bT,
                   float* Cd, int cpitch, float* Cd2,
                   int nrt, int nct, int rowbase, int colbase,
                   unsigned short* FRAG) {
  const int t = threadIdx.x;
  __syncthreads();
  {
    const int slot = t >> 1;
    const int jh = (t & 1) * 4;
    const int l = slot & 63;
    const int Tq = slot >> 6;
    const int mrow = (Tq >> 1) * 16 + (l & 15);
    const int kk = (Tq & 1) * 32 + (l >> 4) * 8 + jh;
    const float4 f = *(const float4*)(Ag + mrow * MP + kk);
    ushort4 H, L;
    unsigned short h;
    h = bf16r(f.x); H.x = h; L.x = bf16r(f.x - bf2f(h));
    h = bf16r(f.y); H.y = h; L.y = bf16r(f.y - bf2f(h));
    h = bf16r(f.z); H.z = h; L.z = bf16r(f.z - bf2f(h));
    h = bf16r(f.w); H.w = h; L.w = bf16r(f.w - bf2f(h));
    *(ushort4*)(FRAG + slot * 8 + jh) = H;
    *(ushort4*)(FRAG + 4096 + slot * 8 + jh) = L;
    float y0, y1, y2, y3;
    if (bT) {
      const float4 g = *(const float4*)(Bs + mrow * MP + kk);
      y0 = g.x; y1 = g.y; y2 = g.z; y3 = g.w;
    } else {
      y0 = Bs[(kk + 0) * MP + mrow]; y1 = Bs[(kk + 1) * MP + mrow];
      y2 = Bs[(kk + 2) * MP + mrow]; y3 = Bs[(kk + 3) * MP + mrow];
    }
    h = bf16r(y0); H.x = h; L.x = bf16r(y0 - bf2f(h));
    h = bf16r(y1); H.y = h; L.y = bf16r(y1 - bf2f(h));
    h = bf16r(y2); H.z = h; L.z = bf16r(y2 - bf2f(h));
    h = bf16r(y3); H.w = h; L.w = bf16r(y3 - bf2f(h));
    *(ushort4*)(FRAG + 8192 + slot * 8 + jh) = H;
    *(ushort4*)(FRAG + 12288 + slot * 8 + jh) = L;
  }
  __syncthreads();
  {
    const int w = t >> 6, l = t & 63;
    if (w < 4 && w < nrt) {
      const v8s Ah0 = *(const v8s*)(FRAG + ((w * 2 + 0) * 64 + l) * 8);
      const v8s Ah1 = *(const v8s*)(FRAG + ((w * 2 + 1) * 64 + l) * 8);
      const v8s Al0 = *(const v8s*)(FRAG + 4096 + ((w * 2 + 0) * 64 + l) * 8);
      const v8s Al1 = *(const v8s*)(FRAG + 4096 + ((w * 2 + 1) * 64 + l) * 8);
      for (int Cc = 0; Cc < nct; ++Cc) {
        const v8s Bh0 = *(const v8s*)(FRAG + 8192 + ((Cc * 2 + 0) * 64 + l) * 8);
        const v8s Bh1 = *(const v8s*)(FRAG + 8192 + ((Cc * 2 + 1) * 64 + l) * 8);
        const v8s Bl0 = *(const v8s*)(FRAG + 12288 + ((Cc * 2 + 0) * 64 + l) * 8);
        const v8s Bl1 = *(const v8s*)(FRAG + 12288 + ((Cc * 2 + 1) * 64 + l) * 8);
        v4f acc = {0.f, 0.f, 0.f, 0.f};
        acc = __builtin_amdgcn_mfma_f32_16x16x32_bf16(Ah0, Bh0, acc, 0, 0, 0);
        acc = __builtin_amdgcn_mfma_f32_16x16x32_bf16(Ah1, Bh1, acc, 0, 0, 0);
        acc = __builtin_amdgcn_mfma_f32_16x16x32_bf16(Ah0, Bl0, acc, 0, 0, 0);
        acc = __builtin_amdgcn_mfma_f32_16x16x32_bf16(Ah1, Bl1, acc, 0, 0, 0);
        acc = __builtin_amdgcn_mfma_f32_16x16x32_bf16(Al0, Bh0, acc, 0, 0, 0);
        acc = __builtin_amdgcn_mfma_f32_16x16x32_bf16(Al1, Bh1, acc, 0, 0, 0);
        const int col = colbase + Cc * 16 + (l & 15);
        const int r0 = rowbase + w * 16 + (l >> 4) * 4;
        Cd[(r0 + 0) * cpitch + col] = acc[0];
        Cd[(r0 + 1) * cpitch + col] = acc[1];
        Cd[(r0 + 2) * cpitch + col] = acc[2];
        Cd[(r0 + 3) * cpitch + col] = acc[3];
        if (Cd2) {
          Cd2[(r0 + 0) * MP + col] = acc[0];
          Cd2[(r0 + 1) * MP + col] = acc[1];
          Cd2[(r0 + 2) * MP + col] = acc[2];
          Cd2[(r0 + 3) * MP + col] = acc[3];
        }
      }
    }
  }
  __syncthreads();
}

// vout = M*vin, M rows pitch MP (LDS or global).
__device__ __forceinline__ void mv64row(const float* M, const float* vin,
                                        float* vout, float* vscr) {
  __syncthreads();
  const int t = threadIdx.x, i = t & 63, c = t >> 6;
  const float4 m = *(const float4*)(M + i * MP + c * 4);
  vscr[t] = fmaf(m.x, vin[c * 4 + 0], fmaf(m.y, vin[c * 4 + 1],
            fmaf(m.z, vin[c * 4 + 2], m.w * vin[c * 4 + 3])));
  __syncthreads();
  if (t < 64) {
    float s = 0.f;
#pragma unroll
    for (int cc = 0; cc < 16; ++cc) s += vscr[cc * 64 + t];
    vout[t] = s;
  }
  __syncthreads();
}

// vout = M^T*vin (column dots on S0 in LDS; conflict-free scalar reads).
__device__ __forceinline__ void mv64colT(const float* M, const float* vin,
                                         float* vout, float* vscr) {
  __syncthreads();
  const int t = threadIdx.x, i = t & 63, c = t >> 6;
  float p = 0.f;
#pragma unroll
  for (int j = 0; j < 4; ++j) p = fmaf(M[(c * 4 + j) * MP + i], vin[c * 4 + j], p);
  vscr[t] = p;
  __syncthreads();
  if (t < 64) {
    float s = 0.f;
#pragma unroll
    for (int cc = 0; cc < 16; ++cc) s += vscr[cc * 64 + t];
    vout[t] = s;
  }
  __syncthreads();
}

// dst = c0*I + c1*X + c2*X2 + c3*X3 (+ addsrc). Element-wise, pitch MP.
__device__ void buildG(float* dst, const float* X, const float* X2, const float* X3,
                       float c0, float c1, float c2, float c3, const float* addsrc) {
  __syncthreads();
  for (int e = threadIdx.x; e < MB; e += NT) {
    const int r = e / MP, c = e - r * MP;
    if (c < 64) {
      float v = c1 * X[e] + c2 * X2[e] + c3 * X3[e];
      if (r == c) v += c0;
      if (addsrc) v += addsrc[e];
      dst[e] = v;
    }
  }
  __syncthreads();
}

__global__ __launch_bounds__(NT) void s4_setup(const float* __restrict__ u,
    const float* __restrict__ A, const float* __restrict__ Bv,
    const float* __restrict__ Cv, const float* __restrict__ logdt,
    float* __restrict__ ws) {
  if (blockIdx.x > 0) {
    const int idx = (blockIdx.x - 1) * NT + threadIdx.x;  // 0..16383
    ws[4096 + idx] = u[(size_t)idx * 1024];
    return;
  }
  __shared__ __align__(16) float S0[MB];
  __shared__ __align__(16) unsigned short FRAG[16384];
  __shared__ float vB[64], v1[64], v2[64], v3[64], va[64], vb[64], vg[64];
  __shared__ int s_s;
  float* vscr = (float*)FRAG;  // overlay: mv* and mm never overlap

  const int t = threadIdx.x;
  float* kbuf = ws;
  float* gX   = ws + 20480;
  float* gX2  = ws + 24832;
  float* gX3  = ws + 29184;
  float* gU0  = ws + 33536;
  float* gU1  = ws + 37888;
  float* gBRT = ws + 42240;
  float* gCQT = ws + 46592;
  const float dt = expf(logdt[0]);

  const float invf[17] = {1.f, 1.f, 1.f / 2.f, 1.f / 6.f, 1.f / 24.f, 1.f / 120.f,
                          1.f / 720.f, 1.f / 5040.f, 1.f / 40320.f, 1.f / 362880.f,
                          1.f / 3628800.f, 1.f / 39916800.f, 1.f / 479001600.f,
                          1.f / 6.2270208e9f, 1.f / 8.71782912e10f,
                          1.f / 1.307674368e12f, 1.f / 2.0922789888e13f};

  // ---- 1-norm of dt*A -> s (theta = 2) ----
  {
    const int j = t & 63, ch = t >> 6;
    float p = 0.f;
#pragma unroll
    for (int ii = 0; ii < 4; ++ii) p += fabsf(A[(ch * 4 + ii) * 64 + j]);
    vscr[t] = p;
    __syncthreads();
    if (t < 64) {
      float cs = 0.f;
#pragma unroll
      for (int c = 0; c < 16; ++c) cs += vscr[c * 64 + t];
      cs *= dt;
#pragma unroll
      for (int off = 32; off > 0; off >>= 1) cs = fmaxf(cs, __shfl_xor(cs, off));
      if (t == 0) {
        int s = 0;
        while (cs > 2.0f && s < 30) { cs *= 0.5f; ++s; }
        s_s = s;
      }
    }
    __syncthreads();
  }
  const int sq = s_s;
  const float scl = ldexpf(dt, -sq);

  // ---- X -> S0 and gX ----
  {
    const float4 a4 = *(const float4*)(A + t * 4);
    float4 x;
    x.x = a4.x * scl; x.y = a4.y * scl; x.z = a4.z * scl; x.w = a4.w * scl;
    const int r = t >> 4, c4 = (t & 15) * 4;
    *(float4*)(S0 + r * MP + c4) = x;
    *(float4*)(gX + r * MP + c4) = x;
  }
  if (t < 64) vB[t] = Bv[t];

  // ---- powers: X2 (S0, +gX2), X3 (gX3), X4 (S0 in-place) ----
  mm(S0, S0, 0, S0, MP, gX2, 4, 4, 0, 0, FRAG);   // X2
  mm(gX, S0, 0, gX3, MP, nullptr, 4, 4, 0, 0, FRAG);  // X3 = X*X2
  mm(S0, S0, 0, S0, MP, nullptr, 4, 4, 0, 0, FRAG);   // X4 = X2*X2

  // ---- phi1(X)*B via PS on vectors (deg-15, groups of 4 in X4) ----
  mv64row(gX,  vB, v1, vscr);
  mv64row(gX2, vB, v2, vscr);
  mv64row(gX3, vB, v3, vscr);
  if (t < 64)
    va[t] = invf[13] * vB[t] + invf[14] * v1[t] + invf[15] * v2[t] + invf[16] * v3[t];
  mv64row(S0, va, vb, vscr);
  if (t < 64)
    va[t] = invf[9] * vB[t] + invf[10] * v1[t] + invf[11] * v2[t] + invf[12] * v3[t] + vb[t];
  mv64row(S0, va, vb, vscr);
  if (t < 64)
    va[t] = invf[5] * vB[t] + invf[6] * v1[t] + invf[7] * v2[t] + invf[8] * v3[t] + vb[t];
  mv64row(S0, va, vb, vscr);
  if (t < 64)
    vg[t] = invf[1] * vB[t] + invf[2] * v1[t] + invf[3] * v2[t] + invf[4] * v3[t] + vb[t];

  // ---- e^X: Taylor-15 PS Horner (B-operand X4 in S0) ----
  buildG(gU0, gX, gX2, gX3, invf[12], invf[13], invf[14], invf[15], nullptr);
  mm(gU0, S0, 0, gU1, MP, nullptr, 4, 4, 0, 0, FRAG);
  buildG(gU1, gX, gX2, gX3, invf[8], invf[9], invf[10], invf[11], gU1);
  mm(gU1, S0, 0, gU0, MP, nullptr, 4, 4, 0, 0, FRAG);
  buildG(gU0, gX, gX2, gX3, invf[4], invf[5], invf[6], invf[7], gU0);
  mm(gU0, S0, 0, S0, MP, nullptr, 4, 4, 0, 0, FRAG);  // -> S0 (over X4)
  buildG(S0, gX, gX2, gX3, invf[0], invf[1], invf[2], invf[3], S0);  // S0 = e^X

  // ---- squarings + phi1 doubling: g <- (F+I)g/2 ----
  for (int it = 0; it < sq; ++it) {
    mv64row(S0, vg, va, vscr);
    if (t < 64) vg[t] = 0.5f * (va[t] + vg[t]);
    mm(S0, S0, 0, S0, MP, nullptr, 4, 4, 0, 0, FRAG);
  }
  // S0 = Abar

  // ---- BRT rows 0..15: bbar then Abar^r bbar ----
  __syncthreads();
  if (t < 64) { va[t] = dt * vg[t]; gBRT[t] = dt * vg[t]; }
  {
    float* vc = va; float* vn = vb;
    for (int r = 1; r < 16; ++r) {
      mv64row(S0, vc, vn, vscr);
      if (t < 64) gBRT[r * MP + t] = vn[t];
      float* tmp = vc; vc = vn; vn = tmp;
    }
  }

  // ---- P-chain (in-place) + BRT widenings ----
  mm(S0, S0, 0, S0, MP, nullptr, 4, 4, 0, 0, FRAG);  // P2
  mm(S0, S0, 0, S0, MP, nullptr, 4, 4, 0, 0, FRAG);  // P4
  mm(S0, S0, 0, S0, MP, nullptr, 4, 4, 0, 0, FRAG);  // P8
  mm(S0, S0, 0, S0, MP, nullptr, 4, 4, 0, 0, FRAG);  // P16
  mm(gBRT, S0, 1, gBRT, MP, nullptr, 1, 4, 16, 0, FRAG);  // rows16:32 = BRT0:16*P16^T
  mm(S0, S0, 0, S0, MP, nullptr, 4, 4, 0, 0, FRAG);  // P32
  mm(gBRT, S0, 1, gBRT, MP, nullptr, 2, 4, 32, 0, FRAG);  // rows32:64
  mm(S0, S0, 0, S0, MP, nullptr, 4, 4, 0, 0, FRAG);  // P64

  // ---- CQT rows 0..15: c then (P64^T)^q c ----
  __syncthreads();
  if (t < 64) { va[t] = Cv[t]; gCQT[t] = Cv[t]; }
  {
    float* vc = va; float* vn = vb;
    for (int qx = 1; qx < 16; ++qx) {
      mv64colT(S0, vc, vn, vscr);
      if (t < 64) gCQT[qx * MP + t] = vn[t];
      float* tmp = vc; vc = vn; vn = tmp;
    }
  }

  // ---- A-chain (in-place) + CQT widenings ----
  mm(S0, S0, 0, S0, MP, nullptr, 4, 4, 0, 0, FRAG);  // A128
  mm(S0, S0, 0, S0, MP, nullptr, 4, 4, 0, 0, FRAG);  // A256
  mm(S0, S0, 0, S0, MP, nullptr, 4, 4, 0, 0, FRAG);  // A512
  mm(S0, S0, 0, S0, MP, nullptr, 4, 4, 0, 0, FRAG);  // A1024
  mm(gCQT, S0, 0, gCQT, MP, nullptr, 1, 4, 16, 0, FRAG);  // rows16:32 = CQT0:16*A1024
  mm(S0, S0, 0, S0, MP, nullptr, 4, 4, 0, 0, FRAG);  // A2048
  mm(gCQT, S0, 0, gCQT, MP, nullptr, 2, 4, 32, 0, FRAG);  // rows32:64

  // ---- k[q*64+r] = sum_i CQT[q][i]*BRT[r][i] ----
  mm(gCQT, gBRT, 1, kbuf, 64, nullptr, 4, 4, 0, 0, FRAG);
}

// Fused conv + broadcast: 4096 blocks x 256 threads; block computes 4 y-scalars
// then streams 4 rows x 1024 cols of broadcast float4 stores (write-bound).
__global__ __launch_bounds__(256) void s4_out(const float* __restrict__ ws,
                                              const float* __restrict__ Dp,
                                              float* __restrict__ out) {
  const int bid = blockIdx.x;
  const int b = bid >> 10;
  const int t0 = (bid & 1023) << 2;
  const float* kb = ws;
  const float* ub = ws + 4096 + (b << 12);
  const int tid = threadIdx.x;
  const int t3 = t0 + 3;
  float a0 = 0.f, a1 = 0.f, a2 = 0.f, a3 = 0.f;
  for (int j = tid; j <= t3; j += 256) {
    const float kj = kb[j];
    if (j <= t0)     a0 = fmaf(kj, ub[t0 - j], a0);
    if (j <= t0 + 1) a1 = fmaf(kj, ub[t0 + 1 - j], a1);
    if (j <= t0 + 2) a2 = fmaf(kj, ub[t0 + 2 - j], a2);
    a3 = fmaf(kj, ub[t3 - j], a3);
  }
#pragma unroll
  for (int off = 32; off > 0; off >>= 1) {
    a0 += __shfl_xor(a0, off);
    a1 += __shfl_xor(a1, off);
    a2 += __shfl_xor(a2, off);
    a3 += __shfl_xor(a3, off);
  }
  __shared__ float red[4][4];
  __shared__ float sy[4];
  if ((tid & 63) == 0) {
    const int w = tid >> 6;
    red[0][w] = a0; red[1][w] = a1; red[2][w] = a2; red[3][w] = a3;
  }
  __syncthreads();
  if (tid < 4)
    sy[tid] = red[tid][0] + red[tid][1] + red[tid][2] + red[tid][3] +
              Dp[0] * ub[t0 + tid];
  __syncthreads();
  const int row = tid >> 6, l = tid & 63;
  const float y = sy[row];
  const float4 y4 = make_float4(y, y, y, y);
  float4* dst = (float4*)(out + ((size_t)(b << 12) + t0 + row) * 1024);
  dst[l] = y4; dst[l + 64] = y4; dst[l + 128] = y4; dst[l + 192] = y4;
}

extern "C" void kernel_launch(void* const* d_in, const int* in_sizes, int n_in,
                              void* d_out, int out_size, void* d_ws, size_t ws_size,
                              hipStream_t stream) {
  const float* u  = (const float*)d_in[0];
  const float* A  = (const float*)d_in[1];
  const float* B  = (const float*)d_in[2];
  const float* C  = (const float*)d_in[3];
  const float* D  = (const float*)d_in[4];
  const float* ld = (const float*)d_in[5];
  float* ws = (float*)d_ws;  // needs >= 203776 bytes

  s4_setup<<<17, NT, 0, stream>>>(u, A, B, C, ld, ws);
  s4_out<<<4096, 256, 0, stream>>>(ws, D, (float*)d_out);
}